// Round 5
// baseline (110.721 us; speedup 1.0000x reference)
//
#include <hip/hip_runtime.h>

typedef short bf16x8 __attribute__((ext_vector_type(8)));
typedef float f32x4  __attribute__((ext_vector_type(4)));

#define L_RES 1280
#define A_ATM 14
#define K_NB  30
#define FEAT  656
#define KPAD  672          // 656 padded to 21*32 for the MFMA K-loop
#define NCH   128
#define WAVES 8
#define RPB   5            // residues per persistent block
#define NBLK  (L_RES / RPB)            // 256 blocks = 1 per CU, perfectly uniform
#define AF_STRIDE 680      // start-bank class (5f+q)&7 covers all 8 -> conflict-free b128
#define AF_BYTES (32 * AF_STRIDE * 2)  // 43,520 per buffer
#define LDS_BYTES (2 * AF_BYTES + 2 * 32 * WAVES * 2 * 4)   // 87,040 + 4,096 = 91,136
#define E_OUT_OFF (L_RES * K_NB * NCH)

// fp32 -> bf16 round-to-nearest-even
__device__ __forceinline__ ushort f2bf(float x) {
    union { float f; unsigned u; } v; v.f = x;
    unsigned r = (v.u + 0x7fffu + ((v.u >> 16) & 1u)) >> 16;
    return (ushort)r;
}

// W_edge [656][128] fp32  ->  Wt [128][672] bf16 (k-padded with zeros)
__global__ __launch_bounds__(256) void wt_convert_kernel(const float* __restrict__ W,
                                                         ushort* __restrict__ Wt) {
    int idx = blockIdx.x * 256 + threadIdx.x;   // n*KPAD + k
    if (idx >= NCH * KPAD) return;
    int n = idx / KPAD, k = idx - n * KPAD;
    float v = (k < FEAT) ? W[k * NCH + n] : 0.0f;
    Wt[idx] = f2bf(v);
}

__global__ __launch_bounds__(512, 2) void sidechain_feat_kernel(
    const float* __restrict__ X,
    const int*   __restrict__ ridx,
    const int*   __restrict__ clab,
    const int*   __restrict__ Eidx,
    const float* __restrict__ Wpos,
    const float* __restrict__ bpos,
    const ushort* __restrict__ Wt,     // bf16 [128][672]
    const float* __restrict__ gamma,
    const float* __restrict__ beta,
    float* __restrict__ out)
{
    extern __shared__ __align__(16) unsigned char smem[];
    // double-buffered A features (bf16) + double-buffered LN partials
    ushort (*Af)[32][AF_STRIDE]  = reinterpret_cast<ushort (*)[32][AF_STRIDE]>(smem);
    float  (*part)[32][WAVES][2] = reinterpret_cast<float (*)[32][WAVES][2]>(smem + 2 * AF_BYTES);

    const int i0   = blockIdx.x * RPB; // first residue of this block
    const int t    = threadIdx.x;
    const int w    = t >> 6;           // wave 0..7
    const int lane = t & 63;
    const int frow = lane & 15;
    const int quad = lane >> 4;
    const int c0   = w * 16 + frow;    // wave's fixed output column

    // ---- persistent B: wave's 16-col Wt slice in registers (21 x bf16x8 = 84 VGPR),
    //      read from L2/L3 ONCE per block (44 MB total vs 220 MB before) ----
    const ushort* B0p = Wt + (size_t)c0 * KPAD + quad * 8;
    bf16x8 B[21];
#pragma unroll
    for (int c = 0; c < 21; ++c) B[c] = *(const bf16x8*)(B0p + c * 32);
    const float gg = gamma[c0], be = beta[c0];

    // ---- feature phase for residue i into buffer pb (compile-time-free indexing) ----
    auto features = [&](int i, int pb) {
        // E_idx passthrough
        if (t < K_NB)
            out[E_OUT_OFF + i * K_NB + t] = (float)Eidx[i * K_NB + t];
        const int my_clab = clab[i];   // block-uniform (L1 broadcast)
        const int my_ridx = ridx[i];
        // positional features (cols 0..15): 480 items + zero the k-pad cols
        if (t < K_NB * 16) {
            int e = t >> 4, c = t & 15;
            int j = Eidx[i * K_NB + e];
            int d;
            if (my_clab == clab[j]) {
                int off = my_ridx - ridx[j] + 32;
                d = off < 0 ? 0 : (off > 64 ? 64 : off);
            } else {
                d = 65;
            }
            Af[pb][e][c] = f2bf(Wpos[d * 16 + c] + bpos[c]);
            Af[pb][e][FEAT + c] = 0;   // garbage NaN x Wt-pad 0 would poison C
        }
        // rows 30,31 stay garbage: they only feed discarded C rows 30,31
        // RBF features: 1200 (edge, pair) items, direct X gathers
#pragma unroll
        for (int u = 0; u < 3; ++u) {
            int idx = t + u * 512;
            if (idx < K_NB * 40) {
                int e  = idx / 40;
                int pp = idx - e * 40;
                int ab = pp / 10, as = pp - ab * 10;
                const int perm[4] = {1, 0, 2, 3};
                int j = Eidx[i * K_NB + e];
                const float* xb = X + (size_t)(i * A_ATM + perm[ab]) * 3;  // L1 broadcast
                const float* xp = X + (size_t)(j * A_ATM + 4 + as) * 3;
                float dx = xb[0] - xp[0];
                float dy = xb[1] - xp[1];
                float dz = xb[2] - xp[2];
                float dist = sqrtf(dx * dx + dy * dy + dz * dz + 1e-6f);
                bool self = (j == i); // AUTOREGRESSIVE: zero RBF on self edges
                unsigned* dst = (unsigned*)&Af[pb][e][16 + pp * 16];
#pragma unroll
                for (int q = 0; q < 8; ++q) {
                    float m0 = 2.0f + (float)(2 * q)     * (20.0f / 15.0f);
                    float m1 = 2.0f + (float)(2 * q + 1) * (20.0f / 15.0f);
                    float a0 = (dist - m0) * 0.8f;
                    float a1 = (dist - m1) * 0.8f;
                    float r0 = self ? 0.0f : __expf(-a0 * a0);
                    float r1 = self ? 0.0f : __expf(-a1 * a1);
                    unsigned pk;
                    asm("v_cvt_pk_bf16_f32 %0, %1, %2" : "=v"(pk) : "v"(r0), "v"(r1));
                    dst[q] = pk;
                }
            }
        }
    };

    // prologue: features for residue 0
    features(i0, 0);
    __syncthreads();

#pragma unroll 1
    for (int rr = 0; rr < RPB; ++rr) {
        const int p = rr & 1;
        // issue next residue's features into the alternate buffer (overlaps GEMM
        // across waves; single barrier below covers both Af[p^1] and part[p])
        if (rr + 1 < RPB) features(i0 + rr + 1, p ^ 1);

        // ---- MFMA GEMM: C[32 x 128] = Af[p][32 x 672] @ B(regs); zero B traffic ----
        const ushort* A0p = &Af[p][frow][quad * 8];
        const ushort* A1p = &Af[p][16 + frow][quad * 8];
        f32x4 acc0 = {0.f,0.f,0.f,0.f}, acc1 = {0.f,0.f,0.f,0.f};
#pragma unroll
        for (int c = 0; c < 21; ++c) {
            bf16x8 a0 = *(const bf16x8*)(A0p + c * 32);
            bf16x8 a1 = *(const bf16x8*)(A1p + c * 32);
            acc0 = __builtin_amdgcn_mfma_f32_16x16x32_bf16(a0, B[c], acc0, 0, 0, 0);
            acc1 = __builtin_amdgcn_mfma_f32_16x16x32_bf16(a1, B[c], acc1, 0, 0, 0);
        }

        // ---- register LayerNorm partials: 16-lane butterfly per wave ----
        // C/D layout (verified m89/m91): col = lane&15, row = quad*4 + reg
        float s0[4], q0[4], s1[4], q1[4];
#pragma unroll
        for (int r = 0; r < 4; ++r) {
            s0[r] = acc0[r];  q0[r] = acc0[r] * acc0[r];
            s1[r] = acc1[r];  q1[r] = acc1[r] * acc1[r];
        }
#pragma unroll
        for (int off = 1; off < 16; off <<= 1) {
#pragma unroll
            for (int r = 0; r < 4; ++r) {
                s0[r] += __shfl_xor(s0[r], off);
                q0[r] += __shfl_xor(q0[r], off);
                s1[r] += __shfl_xor(s1[r], off);
                q1[r] += __shfl_xor(q1[r], off);
            }
        }
        if (frow == 0) {
#pragma unroll
            for (int r = 0; r < 4; ++r) {
                int row = quad * 4 + r;
                part[p][row][w][0]      = s0[r];
                part[p][row][w][1]      = q0[r];
                part[p][16 + row][w][0] = s1[r];
                part[p][16 + row][w][1] = q1[r];
            }
        }
        __syncthreads();               // the ONE barrier: part[p] + Af[p^1] ready

        // ---- finalize LN + store straight from accumulators ----
        const int ibase = (i0 + rr) * K_NB;
#pragma unroll
        for (int r = 0; r < 4; ++r) {
            int row = quad * 4 + r;    // 0..15, always valid
            {
                f32x4 pA = *(const f32x4*)&part[p][row][0][0];
                f32x4 pB = *(const f32x4*)&part[p][row][2][0];
                f32x4 pC = *(const f32x4*)&part[p][row][4][0];
                f32x4 pD = *(const f32x4*)&part[p][row][6][0];
                float S = pA[0]+pA[2]+pB[0]+pB[2]+pC[0]+pC[2]+pD[0]+pD[2];
                float Q = pA[1]+pA[3]+pB[1]+pB[3]+pC[1]+pC[3]+pD[1]+pD[3];
                float mean = S * (1.0f / 128.0f);
                float rstd = rsqrtf(Q * (1.0f / 128.0f) - mean * mean + 1e-5f);
                out[(size_t)(ibase + row) * NCH + c0] = (acc0[r] - mean) * rstd * gg + be;
            }
            int row1 = 16 + row;       // 16..31; rows 30,31 discarded
            if (row1 < K_NB) {
                f32x4 pA = *(const f32x4*)&part[p][row1][0][0];
                f32x4 pB = *(const f32x4*)&part[p][row1][2][0];
                f32x4 pC = *(const f32x4*)&part[p][row1][4][0];
                f32x4 pD = *(const f32x4*)&part[p][row1][6][0];
                float S = pA[0]+pA[2]+pB[0]+pB[2]+pC[0]+pC[2]+pD[0]+pD[2];
                float Q = pA[1]+pA[3]+pB[1]+pB[3]+pC[1]+pC[3]+pD[1]+pD[3];
                float mean = S * (1.0f / 128.0f);
                float rstd = rsqrtf(Q * (1.0f / 128.0f) - mean * mean + 1e-5f);
                out[(size_t)(ibase + row1) * NCH + c0] = (acc1[r] - mean) * rstd * gg + be;
            }
        }
    }
}

extern "C" void kernel_launch(void* const* d_in, const int* in_sizes, int n_in,
                              void* d_out, int out_size, void* d_ws, size_t ws_size,
                              hipStream_t stream) {
    const float* X     = (const float*)d_in[0];
    const int*   ridx  = (const int*)  d_in[1];
    const int*   clab  = (const int*)  d_in[2];
    const int*   Eidx  = (const int*)  d_in[3];
    // d_in[4] = atom_mask (unused by reference forward)
    const float* Wpos  = (const float*)d_in[5];
    const float* bpos  = (const float*)d_in[6];
    const float* Wedge = (const float*)d_in[7];
    const float* gamma = (const float*)d_in[8];
    const float* beta  = (const float*)d_in[9];
    float* out = (float*)d_out;

    // ws poison fill is unconditional (round-1 evidence) -> using ws is free.
    ushort* Wt = (ushort*)d_ws;   // 128*672*2 = 172,032 B

    wt_convert_kernel<<<(NCH * KPAD + 255) / 256, 256, 0, stream>>>(Wedge, Wt);
    sidechain_feat_kernel<<<NBLK, 512, LDS_BYTES, stream>>>(
        X, ridx, clab, Eidx, Wpos, bpos, Wt, gamma, beta, out);
}

// Round 6
// 109.159 us; speedup vs baseline: 1.0143x; 1.0143x over previous
//
#include <hip/hip_runtime.h>

typedef short bf16x8 __attribute__((ext_vector_type(8)));
typedef float f32x4  __attribute__((ext_vector_type(4)));
typedef unsigned int u32x4 __attribute__((ext_vector_type(4)));

#define L_RES 1280
#define A_ATM 14
#define K_NB  30
#define NEDGE (L_RES * K_NB)   // 38400
#define EPT   48               // edges per block (edge-major tiling, 48 = 3 M-tiles)
#define NBLK  (NEDGE / EPT)    // 800 blocks
#define FEAT  656
#define KPAD  672              // 656 padded to 21*32 for the MFMA K-loop
#define NCH   128
#define WAVES 8
#define AF_STRIDE 680          // row stride 340 dwords = 20 mod 32 -> 8 start-bank classes
#define E_OUT_OFF (L_RES * K_NB * NCH)

// fp32 -> bf16 round-to-nearest-even
__device__ __forceinline__ ushort f2bf(float x) {
    union { float f; unsigned u; } v; v.f = x;
    unsigned r = (v.u + 0x7fffu + ((v.u >> 16) & 1u)) >> 16;
    return (ushort)r;
}

// W_edge [656][128] fp32  ->  Wt [128][672] bf16 (k-padded with zeros)
__global__ __launch_bounds__(256) void wt_convert_kernel(const float* __restrict__ W,
                                                         ushort* __restrict__ Wt) {
    int idx = blockIdx.x * 256 + threadIdx.x;   // n*KPAD + k
    if (idx >= NCH * KPAD) return;
    int n = idx / KPAD, k = idx - n * KPAD;
    float v = (k < FEAT) ? W[k * NCH + n] : 0.0f;
    Wt[idx] = f2bf(v);
}

__global__ __launch_bounds__(512, 4) void sidechain_feat_kernel(
    const float* __restrict__ X,
    const int*   __restrict__ ridx,
    const int*   __restrict__ clab,
    const int*   __restrict__ Eidx,
    const float* __restrict__ Wpos,
    const float* __restrict__ bpos,
    const ushort* __restrict__ Wt,     // bf16 [128][672]
    const float* __restrict__ gamma,
    const float* __restrict__ beta,
    float* __restrict__ out)
{
    __shared__ __align__(16) ushort Af[EPT][AF_STRIDE];   // 65,280 B
    __shared__ __align__(16) float part[EPT][WAVES][2];   //  3,072 B  -> 68,352 total, 2 blk/CU

    const int g0   = blockIdx.x * EPT; // first global edge of this block
    const int t    = threadIdx.x;
    const int w    = t >> 6;           // wave 0..7
    const int lane = t & 63;
    const int frow = lane & 15;
    const int quad = lane >> 4;
    const int c0   = w * 16 + frow;    // wave's output column

    // ---- E_idx passthrough (flat: out row g = i*30+e) ----
    if (t < EPT) out[E_OUT_OFF + g0 + t] = (float)Eidx[g0 + t];

    // ---- B prefetch depth-3 + LN params (independent of features) ----
    const ushort* B0p = Wt + (size_t)c0 * KPAD + quad * 8;
    bf16x8 b0 = *(const bf16x8*)(B0p);
    bf16x8 b1 = *(const bf16x8*)(B0p + 32);
    bf16x8 b2 = *(const bf16x8*)(B0p + 64);
    const float gg = gamma[c0], be = beta[c0];

    // ---- positional features (cols 0..15): 48*16 = 768 items ----
#pragma unroll
    for (int u = 0; u < 2; ++u) {
        int idx = t + u * 512;
        if (idx < EPT * 16) {
            int eg = idx >> 4, c = idx & 15;
            int g = g0 + eg;
            int i = g / K_NB;          // residue of this edge (magic-mul)
            int j = Eidx[g];
            int d;
            if (clab[i] == clab[j]) {
                int off = ridx[i] - ridx[j] + 32;
                d = off < 0 ? 0 : (off > 64 ? 64 : off);
            } else {
                d = 65;
            }
            Af[eg][c] = f2bf(Wpos[d * 16 + c] + bpos[c]);
            Af[eg][FEAT + c] = 0;      // zero k-pad (NaN x Wt-pad 0 would poison C)
        }
    }

    // ---- RBF features: 48*40 = 1920 items, EDGE-MINOR so consecutive lanes hit
    //      consecutive Af rows (bank spread) + 2x ds_write_b128 per item ----
#pragma unroll
    for (int u = 0; u < 4; ++u) {
        int idx = t + u * 512;
        if (idx < EPT * 40) {
            int eg = idx % EPT;        // lane-consecutive -> 8 distinct start banks
            int pr = idx / EPT;        // pair 0..39
            int g = g0 + eg;
            int i = g / K_NB;
            int j = Eidx[g];
            int ab = pr / 10, as = pr - ab * 10;
            int pa = ab < 2 ? 1 - ab : ab;      // perm {1,0,2,3} arithmetically
            const float* xb = X + (size_t)(i * A_ATM + pa) * 3;
            const float* xp = X + (size_t)(j * A_ATM + 4 + as) * 3;
            float dx = xb[0] - xp[0];
            float dy = xb[1] - xp[1];
            float dz = xb[2] - xp[2];
            float dist = sqrtf(dx * dx + dy * dy + dz * dz + 1e-6f);
            bool self = (j == i);      // AUTOREGRESSIVE: zero RBF on self edges
            unsigned pk[8];
#pragma unroll
            for (int q = 0; q < 8; ++q) {
                float m0 = 2.0f + (float)(2 * q)     * (20.0f / 15.0f);
                float m1 = 2.0f + (float)(2 * q + 1) * (20.0f / 15.0f);
                float a0 = (dist - m0) * 0.8f;
                float a1 = (dist - m1) * 0.8f;
                float r0 = self ? 0.0f : __expf(-a0 * a0);
                float r1 = self ? 0.0f : __expf(-a1 * a1);
                asm("v_cvt_pk_bf16_f32 %0, %1, %2" : "=v"(pk[q]) : "v"(r0), "v"(r1));
            }
            u32x4* dst = (u32x4*)&Af[eg][16 + pr * 16];   // 16B-aligned
            u32x4 v0 = {pk[0], pk[1], pk[2], pk[3]};
            u32x4 v1 = {pk[4], pk[5], pk[6], pk[7]};
            dst[0] = v0;
            dst[1] = v1;
        }
    }
    __syncthreads();                   // barrier 1: Af ready

    // ---- MFMA GEMM: C[48 x 128] = Af[48 x 672] @ Wt^T; wave: 3 M-tiles x 16 cols ----
    const ushort* A0p = &Af[frow][quad * 8];
    const ushort* A1p = &Af[16 + frow][quad * 8];
    const ushort* A2p = &Af[32 + frow][quad * 8];
    bf16x8 a0 = *(const bf16x8*)A0p;
    bf16x8 a1 = *(const bf16x8*)A1p;
    bf16x8 a2 = *(const bf16x8*)A2p;

    f32x4 acc0 = {0.f,0.f,0.f,0.f}, acc1 = {0.f,0.f,0.f,0.f}, acc2 = {0.f,0.f,0.f,0.f};

#pragma unroll
    for (int c = 0; c < 21; ++c) {
        bf16x8 ua0 = a0, ua1 = a1, ua2 = a2, ub = b0;
        if (c + 1 < 21) {                                 // depth-1 A prefetch (LDS)
            a0 = *(const bf16x8*)(A0p + (c + 1) * 32);
            a1 = *(const bf16x8*)(A1p + (c + 1) * 32);
            a2 = *(const bf16x8*)(A2p + (c + 1) * 32);
        }
        b0 = b1; b1 = b2;
        if (c + 3 < 21)                                   // depth-3 B prefetch (global/L2)
            b2 = *(const bf16x8*)(B0p + (c + 3) * 32);
        acc0 = __builtin_amdgcn_mfma_f32_16x16x32_bf16(ua0, ub, acc0, 0, 0, 0);
        acc1 = __builtin_amdgcn_mfma_f32_16x16x32_bf16(ua1, ub, acc1, 0, 0, 0);
        acc2 = __builtin_amdgcn_mfma_f32_16x16x32_bf16(ua2, ub, acc2, 0, 0, 0);
    }

    // ---- register LayerNorm partials: 16-lane butterfly per wave ----
    // C/D layout (verified m89/m91): col = lane&15, row = quad*4 + reg
    float s[3][4], q[3][4];
#pragma unroll
    for (int r = 0; r < 4; ++r) {
        s[0][r] = acc0[r];  q[0][r] = acc0[r] * acc0[r];
        s[1][r] = acc1[r];  q[1][r] = acc1[r] * acc1[r];
        s[2][r] = acc2[r];  q[2][r] = acc2[r] * acc2[r];
    }
#pragma unroll
    for (int off = 1; off < 16; off <<= 1) {
#pragma unroll
        for (int m = 0; m < 3; ++m)
#pragma unroll
            for (int r = 0; r < 4; ++r) {
                s[m][r] += __shfl_xor(s[m][r], off);
                q[m][r] += __shfl_xor(q[m][r], off);
            }
    }
    if (frow == 0) {
#pragma unroll
        for (int m = 0; m < 3; ++m)
#pragma unroll
            for (int r = 0; r < 4; ++r) {
                int row = m * 16 + quad * 4 + r;
                part[row][w][0] = s[m][r];
                part[row][w][1] = q[m][r];
            }
    }
    __syncthreads();                   // barrier 2: partials ready

    // ---- finalize LN + store straight from accumulators (all 48 rows valid) ----
    auto finalize = [&](const f32x4& acc, int m) {
#pragma unroll
        for (int r = 0; r < 4; ++r) {
            int row = m * 16 + quad * 4 + r;
            f32x4 pA = *(const f32x4*)&part[row][0][0];
            f32x4 pB = *(const f32x4*)&part[row][2][0];
            f32x4 pC = *(const f32x4*)&part[row][4][0];
            f32x4 pD = *(const f32x4*)&part[row][6][0];
            float S = pA[0]+pA[2]+pB[0]+pB[2]+pC[0]+pC[2]+pD[0]+pD[2];
            float Q = pA[1]+pA[3]+pB[1]+pB[3]+pC[1]+pC[3]+pD[1]+pD[3];
            float mean = S * (1.0f / 128.0f);
            float rstd = rsqrtf(Q * (1.0f / 128.0f) - mean * mean + 1e-5f);
            out[(size_t)(g0 + row) * NCH + c0] = (acc[r] - mean) * rstd * gg + be;
        }
    };
    finalize(acc0, 0);
    finalize(acc1, 1);
    finalize(acc2, 2);
}

extern "C" void kernel_launch(void* const* d_in, const int* in_sizes, int n_in,
                              void* d_out, int out_size, void* d_ws, size_t ws_size,
                              hipStream_t stream) {
    const float* X     = (const float*)d_in[0];
    const int*   ridx  = (const int*)  d_in[1];
    const int*   clab  = (const int*)  d_in[2];
    const int*   Eidx  = (const int*)  d_in[3];
    // d_in[4] = atom_mask (unused by reference forward)
    const float* Wpos  = (const float*)d_in[5];
    const float* bpos  = (const float*)d_in[6];
    const float* Wedge = (const float*)d_in[7];
    const float* gamma = (const float*)d_in[8];
    const float* beta  = (const float*)d_in[9];
    float* out = (float*)d_out;

    // ws poison fill is unconditional (round-1 evidence) -> using ws is free.
    ushort* Wt = (ushort*)d_ws;   // 128*672*2 = 172,032 B

    wt_convert_kernel<<<(NCH * KPAD + 255) / 256, 256, 0, stream>>>(Wedge, Wt);
    sidechain_feat_kernel<<<NBLK, 512, 0, stream>>>(
        X, ridx, clab, Eidx, Wpos, bpos, Wt, gamma, beta, out);
}

// Round 7
// 104.503 us; speedup vs baseline: 1.0595x; 1.0446x over previous
//
#include <hip/hip_runtime.h>

typedef short bf16x8 __attribute__((ext_vector_type(8)));
typedef float f32x4  __attribute__((ext_vector_type(4)));
typedef unsigned int u32x4 __attribute__((ext_vector_type(4)));

#define L_RES 1280
#define A_ATM 14
#define K_NB  30
#define FEAT  656
#define KPAD  672          // 656 padded to 21*32 for the MFMA K-loop
#define NCH   128
#define AF_STRIDE 680      // row stride 340 dwords = 20 mod 32 -> 8 start-bank classes
#define E_OUT_OFF (L_RES * K_NB * NCH)

// fp32 -> bf16 round-to-nearest-even
__device__ __forceinline__ ushort f2bf(float x) {
    union { float f; unsigned u; } v; v.f = x;
    unsigned r = (v.u + 0x7fffu + ((v.u >> 16) & 1u)) >> 16;
    return (ushort)r;
}

// W_edge [656][128] fp32  ->  Wt [128][672] bf16 (k-padded with zeros)
__global__ __launch_bounds__(256) void wt_convert_kernel(const float* __restrict__ W,
                                                         ushort* __restrict__ Wt) {
    int idx = blockIdx.x * 256 + threadIdx.x;   // n*KPAD + k
    if (idx >= NCH * KPAD) return;
    int n = idx / KPAD, k = idx - n * KPAD;
    float v = (k < FEAT) ? W[k * NCH + n] : 0.0f;
    Wt[idx] = f2bf(v);
}

__global__ __launch_bounds__(256, 3) void sidechain_feat_kernel(
    const float* __restrict__ X,
    const int*   __restrict__ ridx,
    const int*   __restrict__ clab,
    const int*   __restrict__ Eidx,
    const float* __restrict__ Wpos,
    const float* __restrict__ bpos,
    const ushort* __restrict__ Wt,     // bf16 [128][672]
    const float* __restrict__ gamma,
    const float* __restrict__ beta,
    float* __restrict__ out)
{
    __shared__ __align__(16) ushort Af[32][AF_STRIDE];   // 43,520 B
    __shared__ float bbs[4][3];
    __shared__ int   nbr[K_NB];
    __shared__ __align__(16) float part[32][4][2];       // per-row (sum, sumsq) per wave

    const int i = blockIdx.x;          // residue
    const int t = threadIdx.x;
    const int w = t >> 6;              // wave 0..3
    const int lane = t & 63;
    const int frow = lane & 15;
    const int quad = lane >> 4;
    const int c0 = (2 * w) * 16 + frow;    // wave's two output columns
    const int c1 = c0 + 16;

    // ---- early independent global prefetch: B chunks 0,1 + gamma/beta ----
    const ushort* B0p = Wt + (size_t)c0 * KPAD + quad * 8;
    const ushort* B1p = Wt + (size_t)c1 * KPAD + quad * 8;
    bf16x8 b0c = *(const bf16x8*)(B0p);
    bf16x8 b1c = *(const bf16x8*)(B1p);
    bf16x8 b0n = *(const bf16x8*)(B0p + 32);
    bf16x8 b1n = *(const bf16x8*)(B1p + 32);
    float gg0 = gamma[c0], gg1 = gamma[c1];
    float be0 = beta[c0],  be1 = beta[c1];

    // ---- coords & neighbor indices ----
    if (t < 12) {
        const int perm[4] = {1, 0, 2, 3};
        int a = t / 3, c = t - a * 3;
        bbs[a][c] = X[(i * A_ATM + perm[a]) * 3 + c];
    }
    if (t < K_NB) nbr[t] = Eidx[i * K_NB + t];
    __syncthreads();                     // barrier 1: nbr/bbs ready

    const int my_clab = clab[i];         // block-uniform
    const int my_ridx = ridx[i];

    // ---- positional features (cols 0..15): 480 items ----
#pragma unroll
    for (int u = 0; u < 2; ++u) {
        int idx = t + u * 256;
        if (idx < K_NB * 16) {
            int e = idx >> 4, c = idx & 15;
            int j = nbr[e];
            int d;
            if (my_clab == clab[j]) {
                int off = my_ridx - ridx[j] + 32;
                d = off < 0 ? 0 : (off > 64 ? 64 : off);
            } else {
                d = 65;
            }
            Af[e][c] = f2bf(Wpos[d * 16 + c] + bpos[c]);
        }
    }
    // ---- zero k-pad cols 656..671 of rows 0..29 (rows 30/31 stay garbage:
    //      they only feed discarded C rows 30/31) ----
#pragma unroll
    for (int u = 0; u < 2; ++u) {
        int k = t + u * 256;
        if (k < K_NB * 16) Af[k >> 4][FEAT + (k & 15)] = 0;
    }
    // ---- RBF features: 1200 items, EDGE-MINOR (consecutive lanes -> consecutive
    //      Af rows: 8 start-bank classes vs 4) + 2x ds_write_b128 vs 8x b32 ----
#pragma unroll
    for (int u = 0; u < 5; ++u) {
        int idx = t + u * 256;
        if (idx < K_NB * 40) {
            int eg = idx % K_NB;         // edge (lane-consecutive -> bank spread)
            int pr = idx / K_NB;         // pair 0..39
            int ab = pr / 10, as = pr - ab * 10;
            int j = nbr[eg];
            const float* xp = X + (size_t)(j * A_ATM + 4 + as) * 3;
            float dx = bbs[ab][0] - xp[0];
            float dy = bbs[ab][1] - xp[1];
            float dz = bbs[ab][2] - xp[2];
            float dist = sqrtf(dx * dx + dy * dy + dz * dz + 1e-6f);
            bool self = (j == i);        // AUTOREGRESSIVE: zero RBF on self edges
            unsigned pk[8];
#pragma unroll
            for (int q = 0; q < 8; ++q) {
                float m0 = 2.0f + (float)(2 * q)     * (20.0f / 15.0f);
                float m1 = 2.0f + (float)(2 * q + 1) * (20.0f / 15.0f);
                float a0 = (dist - m0) * 0.8f;
                float a1 = (dist - m1) * 0.8f;
                float r0 = self ? 0.0f : __expf(-a0 * a0);
                float r1 = self ? 0.0f : __expf(-a1 * a1);
                asm("v_cvt_pk_bf16_f32 %0, %1, %2" : "=v"(pk[q]) : "v"(r0), "v"(r1));
            }
            u32x4* dst = (u32x4*)&Af[eg][16 + pr * 16];   // 16B-aligned
            u32x4 v0 = {pk[0], pk[1], pk[2], pk[3]};
            u32x4 v1 = {pk[4], pk[5], pk[6], pk[7]};
            dst[0] = v0;
            dst[1] = v1;
        }
    }
    __syncthreads();                     // barrier 2: Af ready

    // ---- MFMA GEMM: C[32 x 128] = Af[32 x 672] @ Wt^T (bf16 -> fp32) ----
    const ushort* A0p = &Af[frow][quad * 8];
    const ushort* A1p = &Af[16 + frow][quad * 8];
    bf16x8 a0c = *(const bf16x8*)(A0p);
    bf16x8 a1c = *(const bf16x8*)(A1p);

    f32x4 acc00 = {0.f,0.f,0.f,0.f}, acc01 = {0.f,0.f,0.f,0.f};
    f32x4 acc10 = {0.f,0.f,0.f,0.f}, acc11 = {0.f,0.f,0.f,0.f};

#pragma unroll
    for (int c = 0; c < 21; ++c) {
        bf16x8 ua0 = a0c, ua1 = a1c, ub0 = b0c, ub1 = b1c;
        if (c + 1 < 21) {                                 // depth-1 A prefetch (LDS)
            a0c = *(const bf16x8*)(A0p + (c + 1) * 32);
            a1c = *(const bf16x8*)(A1p + (c + 1) * 32);
        }
        b0c = b0n; b1c = b1n;
        if (c + 2 < 21) {                                 // depth-2 B prefetch (global)
            b0n = *(const bf16x8*)(B0p + (c + 2) * 32);
            b1n = *(const bf16x8*)(B1p + (c + 2) * 32);
        }
        acc00 = __builtin_amdgcn_mfma_f32_16x16x32_bf16(ua0, ub0, acc00, 0, 0, 0);
        acc01 = __builtin_amdgcn_mfma_f32_16x16x32_bf16(ua0, ub1, acc01, 0, 0, 0);
        acc10 = __builtin_amdgcn_mfma_f32_16x16x32_bf16(ua1, ub0, acc10, 0, 0, 0);
        acc11 = __builtin_amdgcn_mfma_f32_16x16x32_bf16(ua1, ub1, acc11, 0, 0, 0);
    }

    // ---- register LayerNorm: per-wave 32-col partials via 16-lane butterfly ----
    // C/D layout (verified m89/m91): col = lane&15, row = quad*4 + reg
    float s0[4], q0[4], s1[4], q1[4];
#pragma unroll
    for (int r = 0; r < 4; ++r) {
        s0[r] = acc00[r] + acc01[r];
        q0[r] = acc00[r] * acc00[r] + acc01[r] * acc01[r];
        s1[r] = acc10[r] + acc11[r];
        q1[r] = acc10[r] * acc10[r] + acc11[r] * acc11[r];
    }
#pragma unroll
    for (int off = 1; off < 16; off <<= 1) {
#pragma unroll
        for (int r = 0; r < 4; ++r) {
            s0[r] += __shfl_xor(s0[r], off);
            q0[r] += __shfl_xor(q0[r], off);
            s1[r] += __shfl_xor(s1[r], off);
            q1[r] += __shfl_xor(q1[r], off);
        }
    }
    if (frow == 0) {
#pragma unroll
        for (int r = 0; r < 4; ++r) {
            int row = quad * 4 + r;
            part[row][w][0]      = s0[r];
            part[row][w][1]      = q0[r];
            part[16 + row][w][0] = s1[r];
            part[16 + row][w][1] = q1[r];
        }
    }
    __syncthreads();                     // barrier 3: partials ready

    // ---- finalize LN + store straight from accumulators ----
#pragma unroll
    for (int r = 0; r < 4; ++r) {
        int row = quad * 4 + r;          // 0..15, always valid
        {
            f32x4 pa = *(const f32x4*)&part[row][0][0];
            f32x4 pb = *(const f32x4*)&part[row][2][0];
            float S = pa[0] + pa[2] + pb[0] + pb[2];
            float Q = pa[1] + pa[3] + pb[1] + pb[3];
            float mean = S * (1.0f / 128.0f);
            float rstd = rsqrtf(Q * (1.0f / 128.0f) - mean * mean + 1e-5f);
            float* o = out + (size_t)(i * K_NB + row) * NCH;
            o[c0] = (acc00[r] - mean) * rstd * gg0 + be0;
            o[c1] = (acc01[r] - mean) * rstd * gg1 + be1;
        }
        int row1 = 16 + row;             // 16..31; rows 30/31 discarded
        if (row1 < K_NB) {
            f32x4 pa = *(const f32x4*)&part[row1][0][0];
            f32x4 pb = *(const f32x4*)&part[row1][2][0];
            float S = pa[0] + pa[2] + pb[0] + pb[2];
            float Q = pa[1] + pa[3] + pb[1] + pb[3];
            float mean = S * (1.0f / 128.0f);
            float rstd = rsqrtf(Q * (1.0f / 128.0f) - mean * mean + 1e-5f);
            float* o = out + (size_t)(i * K_NB + row1) * NCH;
            o[c0] = (acc10[r] - mean) * rstd * gg0 + be0;
            o[c1] = (acc11[r] - mean) * rstd * gg1 + be1;
        }
    }

    // ---- E_idx passthrough (as float) ----
    if (t < K_NB) out[E_OUT_OFF + i * K_NB + t] = (float)nbr[t];
}

extern "C" void kernel_launch(void* const* d_in, const int* in_sizes, int n_in,
                              void* d_out, int out_size, void* d_ws, size_t ws_size,
                              hipStream_t stream) {
    const float* X     = (const float*)d_in[0];
    const int*   ridx  = (const int*)  d_in[1];
    const int*   clab  = (const int*)  d_in[2];
    const int*   Eidx  = (const int*)  d_in[3];
    // d_in[4] = atom_mask (unused by reference forward)
    const float* Wpos  = (const float*)d_in[5];
    const float* bpos  = (const float*)d_in[6];
    const float* Wedge = (const float*)d_in[7];
    const float* gamma = (const float*)d_in[8];
    const float* beta  = (const float*)d_in[9];
    float* out = (float*)d_out;

    // ws poison fill is unconditional (round-1 evidence) -> using ws is free.
    ushort* Wt = (ushort*)d_ws;   // 128*672*2 = 172,032 B

    wt_convert_kernel<<<(NCH * KPAD + 255) / 256, 256, 0, stream>>>(Wedge, Wt);
    sidechain_feat_kernel<<<L_RES, 256, 0, stream>>>(
        X, ridx, clab, Eidx, Wpos, bpos, Wt, gamma, beta, out);
}